// Round 5
// baseline (498.811 us; speedup 1.0000x reference)
//
#include <hip/hip_runtime.h>

namespace {
constexpr int BATCH = 512;
constexpr int SEQL  = 512;
constexpr int HID   = 256;
constexpr int MORPH = 24;
constexpr float NEGV = -1.0e9f;
constexpr int NBLK  = 1024;   // 4 blocks/CU needed; >=8 capacity => co-resident
constexpr int NTHR  = 256;
}

__device__ __forceinline__ unsigned okey(float f) {
    unsigned u = __float_as_uint(f);
    return u ^ (unsigned)(((int)u >> 31) | 0x80000000);
}

// device-scope grid barrier; ctr zeroed by hipMemsetAsync each launch
__device__ __forceinline__ void gbar(unsigned* ctr, unsigned nb) {
    __syncthreads();
    if (threadIdx.x == 0) {
        __threadfence();  // release: flush this block's writes to device scope
        __hip_atomic_fetch_add(ctr, 1u, __ATOMIC_ACQ_REL, __HIP_MEMORY_SCOPE_AGENT);
        while (__hip_atomic_load(ctr, __ATOMIC_ACQUIRE, __HIP_MEMORY_SCOPE_AGENT) < nb)
            __builtin_amdgcn_s_sleep(2);
    }
    __syncthreads();
}

extern "C" __global__ __launch_bounds__(NTHR, 8)
void morphseg_fused(const float* __restrict__ we, const int* __restrict__ wlen,
                    const int* __restrict__ nmorph, const float* __restrict__ Wv,
                    const float* __restrict__ bias, float* __restrict__ out,
                    unsigned* __restrict__ keys, int* __restrict__ sep,
                    unsigned* __restrict__ bar)
{
    const int tid = threadIdx.x, lane = tid & 63, wave = tid >> 6;

    __shared__ unsigned s_keys[SEQL];
    __shared__ int s_hist[256];
    __shared__ int s_c2m[SEQL];
    __shared__ unsigned long long s_eqm[8], s_ind[8];
    __shared__ unsigned s_p, s_T;
    __shared__ int s_Kr, s_KrF, s_done;

    const float4 w4 = reinterpret_cast<const float4*>(Wv)[lane];
    const float b0 = bias[0];
    const unsigned KEYNEG = okey(NEGV);

    // ---- Phase A: keys for all (b, 64-row chunk); grid-stride over 4096 units
    for (int unit = blockIdx.x; unit < BATCH * 8; unit += NBLK) {
        const int b = unit >> 3, q = unit & 7;
        const int nvalid = wlen[b] - 1;
        const float* __restrict__ werow = we + (size_t)b * (SEQL * HID);
        const int rs = q * 64;
        for (int l = rs + wave; l < rs + 64; l += 4) {
            unsigned kk = KEYNEG;
            if (l < nvalid) {                 // wave-uniform
                const float4 v = reinterpret_cast<const float4*>(werow + (size_t)l * HID)[lane];
                float p = v.x * w4.x + v.y * w4.y + v.z * w4.z + v.w * w4.w;
                #pragma unroll
                for (int off = 32; off >= 1; off >>= 1)
                    p += __shfl_xor(p, off, 64);
                kk = okey(p + b0);
            }
            if (lane == 0) keys[b * SEQL + l] = kk;
        }
    }
    gbar(&bar[0], NBLK);

    // ---- Phase B: per-b radix select -> sep list + bpm (blocks 0..511)
    if (blockIdx.x < BATCH) {
        const int b = blockIdx.x;
        const int wl = wlen[b];
        const int nm = nmorph[b];
        const int K  = nm - 1;

        s_keys[tid]       = keys[b * SEQL + tid];
        s_keys[tid + 256] = keys[b * SEQL + tid + 256];
        if (tid == 0) { s_p = 0u; s_Kr = K; s_done = 0; }
        __syncthreads();

        int done = 0;
        for (int pass = 0; pass < 4 && !done; ++pass) {
            const int shift = 24 - 8 * pass;
            s_hist[tid] = 0;
            __syncthreads();
            {
                const unsigned p = s_p;
                const unsigned k0 = s_keys[tid], k1 = s_keys[tid + 256];
                if (pass == 0 || (k0 >> (shift + 8)) == (p >> (shift + 8)))
                    atomicAdd(&s_hist[(k0 >> shift) & 255], 1);
                if (pass == 0 || (k1 >> (shift + 8)) == (p >> (shift + 8)))
                    atomicAdd(&s_hist[(k1 >> shift) & 255], 1);
            }
            __syncthreads();
            if (wave == 0) {
                const int v0 = lane * 4;
                const int h0 = s_hist[v0], h1 = s_hist[v0 + 1];
                const int h2 = s_hist[v0 + 2], h3 = s_hist[v0 + 3];
                const int local = h0 + h1 + h2 + h3;
                int T = local;
                #pragma unroll
                for (int off = 1; off < 64; off <<= 1) {
                    const int u = __shfl_down(T, off, 64);
                    if (lane + off < 64) T += u;
                }
                const int A  = T - local;
                const int S3 = A + h3, S2 = S3 + h2, S1 = S2 + h1, S0 = S1 + h0;
                const int Kr = s_Kr;
                const unsigned p = s_p;
                int v = -1, Sv = 0, Sv1 = 0;
                if (A  < Kr && Kr <= S3) { v = v0 + 3; Sv = S3; Sv1 = A;  }
                if (S3 < Kr && Kr <= S2) { v = v0 + 2; Sv = S2; Sv1 = S3; }
                if (S2 < Kr && Kr <= S1) { v = v0 + 1; Sv = S1; Sv1 = S2; }
                if (S1 < Kr && Kr <= S0) { v = v0 + 0; Sv = S0; Sv1 = S1; }
                if (v >= 0) {
                    const unsigned pv = p | ((unsigned)v << shift);
                    if (Sv == Kr)        { s_T = pv - 1u; s_KrF = 0;        s_done = 1; }
                    else if (shift == 0) { s_T = pv;      s_KrF = Kr - Sv1; s_done = 1; }
                    else                 { s_p = pv;      s_Kr = Kr - Sv1; }
                }
            }
            __syncthreads();
            done = s_done;
        }

        const unsigned Tf = s_T;
        const int KrF = s_KrF;
        const unsigned k0 = s_keys[tid], k1 = s_keys[tid + 256];
        const bool gt0 = (k0 > Tf), eq0 = (k0 == Tf);
        const bool gt1 = (k1 > Tf), eq1 = (k1 == Tf);
        const unsigned long long e0 = __ballot(eq0), e1 = __ballot(eq1);
        if (lane == 0) { s_eqm[wave] = e0; s_eqm[wave + 4] = e1; }
        __syncthreads();

        auto prefix8 = [&](const unsigned long long* w8, int pos) -> int {
            const int wi = pos >> 6;
            const unsigned long long lowmask = (1ull << (pos & 63)) - 1ull;
            int r = 0;
            #pragma unroll
            for (int q2 = 0; q2 < 8; ++q2) {
                const unsigned long long w = w8[q2];
                r += (q2 < wi) ? __popcll(w) : ((q2 == wi) ? __popcll(w & lowmask) : 0);
            }
            return r;
        };

        const int f0 = gt0 || (eq0 && prefix8(s_eqm, tid) < KrF);
        const int f1 = gt1 || (eq1 && prefix8(s_eqm, tid + 256) < KrF);
        const unsigned long long fb0 = __ballot(f0), fb1 = __ballot(f1);
        if (lane == 0) { s_ind[wave] = fb0; s_ind[wave + 4] = fb1; }
        __syncthreads();
        {
            const int c0 = prefix8(s_ind, tid);
            const int c1 = prefix8(s_ind, tid + 256);
            s_c2m[tid] = c0;
            s_c2m[tid + 256] = c1;
            if (f0) sep[b * 32 + c0] = tid;
            if (f1) sep[b * 32 + c1] = tid + 256;
        }
        __syncthreads();

        // bpm one-hot, float4 (6 per l-row)
        float* __restrict__ bpm = out + (size_t)BATCH * MORPH * HID + (size_t)b * (SEQL * MORPH);
        for (int v = tid; v < SEQL * MORPH / 4; v += NTHR) {
            const int l  = v / 6;
            const int qv = v - l * 6;
            const int c  = s_c2m[l];
            const int mb = qv * 4;
            const bool valid = (l < wl);
            float4 o;
            o.x = (valid && c == mb + 0 && mb + 0 < nm) ? 1.0f : 0.0f;
            o.y = (valid && c == mb + 1 && mb + 1 < nm) ? 1.0f : 0.0f;
            o.z = (valid && c == mb + 2 && mb + 2 < nm) ? 1.0f : 0.0f;
            o.w = (valid && c == mb + 3 && mb + 3 < nm) ? 1.0f : 0.0f;
            reinterpret_cast<float4*>(bpm)[v] = o;
        }
    }
    gbar(&bar[1], NBLK);

    // ---- Phase C: one morpheme per wave; plain stores, no atomics, no zero pass
    for (int u = blockIdx.x * 4 + wave; u < BATCH * MORPH; u += NBLK * 4) {
        const int b = u / MORPH;
        const int m = u - b * MORPH;
        const int wl = wlen[b], nm = nmorph[b], K = nm - 1;
        float4 a0 = {0,0,0,0}, a1 = {0,0,0,0}, a2 = {0,0,0,0}, a3 = {0,0,0,0};
        if (m < nm) {
            const int lo = (m == 0) ? 0 : sep[b * 32 + m - 1] + 1;
            const int hi = (m < K) ? sep[b * 32 + m] : wl - 1;   // inclusive
            const float* __restrict__ werow = we + (size_t)b * (SEQL * HID);
            int l = lo;
            for (; l + 3 <= hi; l += 4) {
                const float4 v0 = reinterpret_cast<const float4*>(werow + (size_t)(l    ) * HID)[lane];
                const float4 v1 = reinterpret_cast<const float4*>(werow + (size_t)(l + 1) * HID)[lane];
                const float4 v2 = reinterpret_cast<const float4*>(werow + (size_t)(l + 2) * HID)[lane];
                const float4 v3 = reinterpret_cast<const float4*>(werow + (size_t)(l + 3) * HID)[lane];
                a0.x += v0.x; a0.y += v0.y; a0.z += v0.z; a0.w += v0.w;
                a1.x += v1.x; a1.y += v1.y; a1.z += v1.z; a1.w += v1.w;
                a2.x += v2.x; a2.y += v2.y; a2.z += v2.z; a2.w += v2.w;
                a3.x += v3.x; a3.y += v3.y; a3.z += v3.z; a3.w += v3.w;
            }
            for (; l <= hi; ++l) {
                const float4 v0 = reinterpret_cast<const float4*>(werow + (size_t)l * HID)[lane];
                a0.x += v0.x; a0.y += v0.y; a0.z += v0.z; a0.w += v0.w;
            }
        }
        float4 t;
        t.x = (a0.x + a1.x) + (a2.x + a3.x);
        t.y = (a0.y + a1.y) + (a2.y + a3.y);
        t.z = (a0.z + a1.z) + (a2.z + a3.z);
        t.w = (a0.w + a1.w) + (a2.w + a3.w);
        reinterpret_cast<float4*>(out + (size_t)b * (MORPH * HID) + (size_t)m * HID)[lane] = t;
    }
}

extern "C" void kernel_launch(void* const* d_in, const int* in_sizes, int n_in,
                              void* d_out, int out_size, void* d_ws, size_t ws_size,
                              hipStream_t stream) {
    const float* we     = (const float*)d_in[0];
    const int*   wlen   = (const int*)d_in[1];
    const int*   nmorph = (const int*)d_in[2];
    const float* Wv     = (const float*)d_in[3];
    const float* bias   = (const float*)d_in[4];
    float* out = (float*)d_out;

    unsigned* bar  = (unsigned*)d_ws;                              // 512 B
    unsigned* keys = (unsigned*)((char*)d_ws + 512);               // 1 MB
    int*      sep  = (int*)((char*)d_ws + 512 + (1u << 20));       // 64 KB

    hipMemsetAsync(d_ws, 0, 512, stream);   // reset barrier counters each launch
    morphseg_fused<<<dim3(NBLK), dim3(NTHR), 0, stream>>>(
        we, wlen, nmorph, Wv, bias, out, keys, sep, bar);
}

// Round 6
// 71.214 us; speedup vs baseline: 7.0044x; 7.0044x over previous
//
#include <hip/hip_runtime.h>

namespace {
constexpr int BATCH = 512;
constexpr int SEQL  = 512;
constexpr int HID   = 256;
constexpr int MORPH = 24;
constexpr float NEGV = -1.0e9f;
}

__device__ __forceinline__ unsigned okey(float f) {
    unsigned u = __float_as_uint(f);
    return u ^ (unsigned)(((int)u >> 31) | 0x80000000);
}

// ---- Kernel A: order-keys for all (b,l). grid 4096: blk=(b<<3)|q, rows [64q,64q+64).
// 256 thr = 4 waves, wave-per-row float4 matvec + shuffle reduce. Balanced.
extern "C" __global__ __launch_bounds__(256)
void k_scores(const float* __restrict__ we, const int* __restrict__ wlen,
              const float* __restrict__ Wv, const float* __restrict__ bias,
              unsigned* __restrict__ keys)
{
    const int blk = blockIdx.x;
    const int b = blk >> 3, q = blk & 7;
    const int tid = threadIdx.x, lane = tid & 63, wave = tid >> 6;
    const int nvalid = wlen[b] - 1;
    const float b0 = bias[0];
    const float* __restrict__ werow = we + (size_t)b * (SEQL * HID);
    const unsigned KEYNEG = okey(NEGV);
    const float4 w4 = reinterpret_cast<const float4*>(Wv)[lane];
    const int rs = q * 64;

    for (int l = rs + wave; l < rs + 64; l += 4) {
        unsigned kk = KEYNEG;
        if (l < nvalid) {                       // wave-uniform
            const float4 v = reinterpret_cast<const float4*>(werow + (size_t)l * HID)[lane];
            float p = v.x * w4.x + v.y * w4.y + v.z * w4.z + v.w * w4.w;
            #pragma unroll
            for (int off = 32; off >= 1; off >>= 1)
                p += __shfl_xor(p, off, 64);
            kk = okey(p + b0);
        }
        if (lane == 0) keys[b * SEQL + l] = kk;
    }
}

// ---- Kernel B: per-b radix select, then either menc (blocks 0..511, launched
// first) or bpm (blocks 512..1023, backfill). 1024 threads = 16 waves.
extern "C" __global__ __launch_bounds__(1024)
void k_finish(const float* __restrict__ we, const int* __restrict__ wlen,
              const int* __restrict__ nmorph, const unsigned* __restrict__ keys,
              float* __restrict__ out)
{
    const int b     = blockIdx.x & (BATCH - 1);
    const int mtype = blockIdx.x >> 9;          // 0 = menc, 1 = bpm
    const int tid = threadIdx.x, lane = tid & 63, wave = tid >> 6;

    __shared__ unsigned s_keys[SEQL];
    __shared__ int s_hist[256];
    __shared__ int s_c2m[SEQL];
    __shared__ int s_sep[32];
    __shared__ unsigned long long s_eqm[8], s_ind[8];
    __shared__ unsigned s_p, s_T;
    __shared__ int s_Kr, s_KrF, s_done;

    const int wl = wlen[b];
    const int nm = nmorph[b];
    const int K  = nm - 1;

    if (tid < SEQL) s_keys[tid] = keys[b * SEQL + tid];
    if (tid == 0) { s_p = 0u; s_Kr = K; s_done = 0; }
    __syncthreads();

    // radix select, MSB-first, early exit on exact boundary
    int done = 0;
    for (int pass = 0; pass < 4 && !done; ++pass) {
        const int shift = 24 - 8 * pass;
        if (tid < 256) s_hist[tid] = 0;
        __syncthreads();
        if (tid < SEQL) {
            const unsigned k = s_keys[tid];
            if (pass == 0 || (k >> (shift + 8)) == (s_p >> (shift + 8)))
                atomicAdd(&s_hist[(k >> shift) & 255], 1);
        }
        __syncthreads();
        if (wave == 0) {
            const int v0 = lane * 4;
            const int h0 = s_hist[v0], h1 = s_hist[v0 + 1];
            const int h2 = s_hist[v0 + 2], h3 = s_hist[v0 + 3];
            const int local = h0 + h1 + h2 + h3;
            int T = local;
            #pragma unroll
            for (int off = 1; off < 64; off <<= 1) {
                const int u = __shfl_down(T, off, 64);
                if (lane + off < 64) T += u;
            }
            const int A  = T - local;
            const int S3 = A + h3, S2 = S3 + h2, S1 = S2 + h1, S0 = S1 + h0;
            const int Kr = s_Kr;
            const unsigned p = s_p;
            int v = -1, Sv = 0, Sv1 = 0;
            if (A  < Kr && Kr <= S3) { v = v0 + 3; Sv = S3; Sv1 = A;  }
            if (S3 < Kr && Kr <= S2) { v = v0 + 2; Sv = S2; Sv1 = S3; }
            if (S2 < Kr && Kr <= S1) { v = v0 + 1; Sv = S1; Sv1 = S2; }
            if (S1 < Kr && Kr <= S0) { v = v0 + 0; Sv = S0; Sv1 = S1; }
            if (v >= 0) {
                const unsigned pv = p | ((unsigned)v << shift);
                if (Sv == Kr)        { s_T = pv - 1u; s_KrF = 0;        s_done = 1; }
                else if (shift == 0) { s_T = pv;      s_KrF = Kr - Sv1; s_done = 1; }
                else                 { s_p = pv;      s_Kr = Kr - Sv1; }
            }
        }
        __syncthreads();
        done = s_done;
    }

    // separator flags (stable ties), c2m, sep list
    const unsigned Tf = s_T;
    const int KrF = s_KrF;
    const unsigned k = (tid < SEQL) ? s_keys[tid] : 0u;
    const bool gt = (tid < SEQL) && (k > Tf);
    const bool eq = (tid < SEQL) && (k == Tf);
    const unsigned long long eb = __ballot(eq);
    if (lane == 0 && wave < 8) s_eqm[wave] = eb;
    __syncthreads();

    auto prefix8 = [&](const unsigned long long* w8, int pos) -> int {
        const int wi = pos >> 6;
        const unsigned long long lowmask = (1ull << (pos & 63)) - 1ull;
        int r = 0;
        #pragma unroll
        for (int q2 = 0; q2 < 8; ++q2) {
            const unsigned long long w = w8[q2];
            r += (q2 < wi) ? __popcll(w) : ((q2 == wi) ? __popcll(w & lowmask) : 0);
        }
        return r;
    };

    int f = 0;
    if (tid < SEQL) f = gt || (eq && prefix8(s_eqm, tid) < KrF);
    const unsigned long long fb = __ballot(f);
    if (lane == 0 && wave < 8) s_ind[wave] = fb;
    __syncthreads();
    if (tid < SEQL) {
        const int cnt = prefix8(s_ind, tid);
        s_c2m[tid] = cnt;
        if (f) s_sep[cnt] = tid;
    }
    __syncthreads();

    if (mtype == 0) {
        // ---- menc: one morpheme per wave; register acc, plain float4 store
        for (int m = wave; m < MORPH; m += 16) {
            float4 a0 = {0,0,0,0}, a1 = {0,0,0,0}, a2 = {0,0,0,0}, a3 = {0,0,0,0};
            if (m < nm) {
                const int lo = (m == 0) ? 0 : s_sep[m - 1] + 1;
                const int hi = (m < K) ? s_sep[m] : wl - 1;   // inclusive
                const float* __restrict__ werow = we + (size_t)b * (SEQL * HID);
                int l = lo;
                for (; l + 3 <= hi; l += 4) {
                    const float4 v0 = reinterpret_cast<const float4*>(werow + (size_t)(l    ) * HID)[lane];
                    const float4 v1 = reinterpret_cast<const float4*>(werow + (size_t)(l + 1) * HID)[lane];
                    const float4 v2 = reinterpret_cast<const float4*>(werow + (size_t)(l + 2) * HID)[lane];
                    const float4 v3 = reinterpret_cast<const float4*>(werow + (size_t)(l + 3) * HID)[lane];
                    a0.x += v0.x; a0.y += v0.y; a0.z += v0.z; a0.w += v0.w;
                    a1.x += v1.x; a1.y += v1.y; a1.z += v1.z; a1.w += v1.w;
                    a2.x += v2.x; a2.y += v2.y; a2.z += v2.z; a2.w += v2.w;
                    a3.x += v3.x; a3.y += v3.y; a3.z += v3.z; a3.w += v3.w;
                }
                for (; l <= hi; ++l) {
                    const float4 v0 = reinterpret_cast<const float4*>(werow + (size_t)l * HID)[lane];
                    a0.x += v0.x; a0.y += v0.y; a0.z += v0.z; a0.w += v0.w;
                }
            }
            float4 t;
            t.x = (a0.x + a1.x) + (a2.x + a3.x);
            t.y = (a0.y + a1.y) + (a2.y + a3.y);
            t.z = (a0.z + a1.z) + (a2.z + a3.z);
            t.w = (a0.w + a1.w) + (a2.w + a3.w);
            reinterpret_cast<float4*>(out + (size_t)b * (MORPH * HID) + (size_t)m * HID)[lane] = t;
        }
    } else {
        // ---- bpm one-hot, float4 (6 per l-row)
        float* __restrict__ bpm = out + (size_t)BATCH * MORPH * HID + (size_t)b * (SEQL * MORPH);
        for (int v = tid; v < SEQL * MORPH / 4; v += 1024) {
            const int l  = v / 6;
            const int qv = v - l * 6;
            const int c  = s_c2m[l];
            const int mb = qv * 4;
            const bool valid = (l < wl);
            float4 o;
            o.x = (valid && c == mb + 0 && mb + 0 < nm) ? 1.0f : 0.0f;
            o.y = (valid && c == mb + 1 && mb + 1 < nm) ? 1.0f : 0.0f;
            o.z = (valid && c == mb + 2 && mb + 2 < nm) ? 1.0f : 0.0f;
            o.w = (valid && c == mb + 3 && mb + 3 < nm) ? 1.0f : 0.0f;
            reinterpret_cast<float4*>(bpm)[v] = o;
        }
    }
}

extern "C" void kernel_launch(void* const* d_in, const int* in_sizes, int n_in,
                              void* d_out, int out_size, void* d_ws, size_t ws_size,
                              hipStream_t stream) {
    const float* we     = (const float*)d_in[0];
    const int*   wlen   = (const int*)d_in[1];
    const int*   nmorph = (const int*)d_in[2];
    const float* Wv     = (const float*)d_in[3];
    const float* bias   = (const float*)d_in[4];
    float* out = (float*)d_out;

    unsigned* keys = (unsigned*)d_ws;   // 1 MB, fully rewritten every launch

    k_scores<<<dim3(BATCH * 8), dim3(256), 0, stream>>>(we, wlen, Wv, bias, keys);
    k_finish<<<dim3(BATCH * 2), dim3(1024), 0, stream>>>(we, wlen, nmorph, keys, out);
}